// Round 26
// baseline (501.234 us; speedup 1.0000x reference)
//
#include <hip/hip_runtime.h>
#include <hip/hip_fp16.h>
#include <math.h>

#define N_NODES 200000
#define N_EDGES 6400000
#define F_INF   512
#define HID     16
#define NCLS    7

#define NPB      1024                              // nodes per bucket
#define NBUCKET  ((N_NODES + NPB - 1) / NPB)       // 196
#define CHUNK    16384
#define NBLKE    ((N_EDGES + CHUNK - 1) / CHUNK)   // 391

// ---- gemm1 (MFMA) geometry ----
#define GROWS 64     // rows per block (4 waves x 16)
#define KCHG  128    // K-chunk in fp32 elems (4 chunks of 128 = 512)
#define ASTR  136    // LDS row stride in halves (272B = 4 banks mod 32 -> <=2-way)
#define GEMM_BLOCKS (N_NODES / GROWS)              // 3125

typedef _Float16 f16x8 __attribute__((ext_vector_type(8)));
typedef float    f32x4 __attribute__((ext_vector_type(4)));

// ======================= pack (W1[0]|W1[1]|root1) into MFMA B-fragment order ========
__global__ __launch_bounds__(256) void packB_kernel(
    const float* __restrict__ W1, const float* __restrict__ root1,
    __half* __restrict__ Bf) {
    int tt = blockIdx.x * 256 + threadIdx.x;    // 3*16*64 = 3072
    if (tt >= 3 * 16 * 64) return;
    int lane = tt & 63, kk = (tt >> 6) & 15, t = tt >> 10;
    int col = lane & 15;
    int kbase = kk * 32 + (lane >> 4) * 8;
    const float* __restrict__ srcm = (t == 0) ? W1
                                   : (t == 1) ? (W1 + F_INF * HID) : root1;
    #pragma unroll
    for (int j = 0; j < 8; ++j)
        Bf[(size_t)tt * 8 + j] = __float2half(srcm[(kbase + j) * HID + col]);
}

// ======================= P1: per-block bucket histogram (int4 loads) =================
__global__ __launch_bounds__(256) void p1_bincount(const int* __restrict__ dst,
                                                   int* __restrict__ blockOff) {
    __shared__ int hist[4][NBUCKET];
    int tid = threadIdx.x, w = tid >> 6;
    for (int i = tid; i < 4 * NBUCKET; i += 256) hist[i / NBUCKET][i % NBUCKET] = 0;
    __syncthreads();
    size_t base = (size_t)blockIdx.x * CHUNK;
    #pragma unroll
    for (int i = 0; i < CHUNK / 1024; ++i) {       // 16 iters x 1024 edges
        size_t e = base + (size_t)i * 1024 + tid * 4;
        if (e < N_EDGES) {                          // tail block is 1024-granular
            int4 d4 = *(const int4*)(dst + e);
            atomicAdd(&hist[w][d4.x >> 10], 1);
            atomicAdd(&hist[w][d4.y >> 10], 1);
            atomicAdd(&hist[w][d4.z >> 10], 1);
            atomicAdd(&hist[w][d4.w >> 10], 1);
        }
    }
    __syncthreads();
    for (int i = tid; i < NBUCKET; i += 256)
        blockOff[(size_t)i * NBLKE + blockIdx.x] =
            hist[0][i] + hist[1][i] + hist[2][i] + hist[3][i];
}

// ======================= P2a: per-bucket scan over blocks =======================
__global__ __launch_bounds__(256) void p2a_kernel(int* __restrict__ blockOff,
                                                  int* __restrict__ bucketTotal) {
    __shared__ int wsum[4];
    int b = blockIdx.x, tid = threadIdx.x;
    size_t rowb = (size_t)b * NBLKE;
    int i0 = tid * 2, i1 = i0 + 1;
    int v0 = (i0 < NBLKE) ? blockOff[rowb + i0] : 0;
    int v1 = (i1 < NBLKE) ? blockOff[rowb + i1] : 0;
    int s = v0 + v1;
    int lane = tid & 63, wid = tid >> 6;
    int incl = s;
    #pragma unroll
    for (int o = 1; o < 64; o <<= 1) {
        int t = __shfl_up(incl, o, 64);
        if (lane >= o) incl += t;
    }
    if (lane == 63) wsum[wid] = incl;
    __syncthreads();
    int woff = 0;
    for (int w = 0; w < wid; ++w) woff += wsum[w];
    int excl = woff + incl - s;
    if (i0 < NBLKE) blockOff[rowb + i0] = excl;
    if (i1 < NBLKE) blockOff[rowb + i1] = excl + v0;
    if (tid == 255) bucketTotal[b] = woff + incl;
}

// ======================= P2b: scan bucket totals -> bucketStart =======================
__global__ __launch_bounds__(256) void p2b_kernel(const int* __restrict__ bucketTotal,
                                                  int* __restrict__ bucketStart,
                                                  int* __restrict__ rowptr) {
    __shared__ int wsum[4];
    int tid = threadIdx.x;
    int base = tid * 4;
    int v[4]; int s = 0;
    #pragma unroll
    for (int q = 0; q < 4; ++q) {
        int idx = base + q;
        v[q] = (idx < NBUCKET) ? bucketTotal[idx] : 0;
        s += v[q];
    }
    int lane = tid & 63, wid = tid >> 6;
    int incl = s;
    #pragma unroll
    for (int o = 1; o < 64; o <<= 1) {
        int t = __shfl_up(incl, o, 64);
        if (lane >= o) incl += t;
    }
    if (lane == 63) wsum[wid] = incl;
    __syncthreads();
    int woff = 0;
    for (int w = 0; w < wid; ++w) woff += wsum[w];
    int run = woff + incl - s;
    #pragma unroll
    for (int q = 0; q < 4; ++q) {
        int idx = base + q;
        if (idx < NBUCKET) bucketStart[idx] = run;
        run += v[q];
    }
    if (tid == 0) rowptr[N_NODES] = N_EDGES;
}

// ============ fused: P3 binned scatter (blocks 0..390) + layer-1 GEMM (rest) =========
// p3 writes ONE 8-byte payload per edge: (local[10b]<<32) | (wq14<<18) | src18.
// gemm path: each wave's LDS tile is PRIVATE (stages & reads only its own 16 rows),
// so no block barriers — waves free-run with compiler-inserted lgkmcnt ordering.
__global__ __launch_bounds__(256) void gemm1p3_kernel(
    const float* __restrict__ x, const __half* __restrict__ Bf,
    __half2* __restrict__ hbufH, __half* __restrict__ rbufH,
    const int* __restrict__ dst, const int* __restrict__ src,
    const float* __restrict__ eattr,
    const int* __restrict__ blockOff, const int* __restrict__ bucketStart,
    unsigned long long* __restrict__ metaW) {
    __shared__ char smem[GROWS * ASTR * 2];      // 17408 B, aliased by both paths
    int tid = threadIdx.x;

    if (blockIdx.x < NBLKE) {
        // ---- P3: binned scatter of payload ----
        int bb = blockIdx.x;
        int* cur = (int*)smem;                   // 196 ints
        for (int i = tid; i < NBUCKET; i += 256)
            cur[i] = bucketStart[i] + blockOff[(size_t)i * NBLKE + bb];
        __syncthreads();
        size_t base = (size_t)bb * CHUNK;
        for (int i = 0; i < CHUNK / 256; ++i) {
            size_t e = base + (size_t)i * 256 + tid;
            if (e < N_EDGES) {
                int d = dst[e];
                int b = d >> 10;
                int slot = atomicAdd(&cur[b], 1);
                float w = fminf(fmaxf(eattr[e], 0.f), 1.f);
                unsigned int wq = (unsigned int)(w * 16383.0f + 0.5f);
                unsigned int lo = (wq << 18) | (unsigned int)src[e];
                metaW[slot] = ((unsigned long long)(d & 1023) << 32) | lo;
            }
        }
    } else {
        // ---- layer-1 GEMM via MFMA (KCHG=128, reg-prefetch, wave-private LDS) ----
        __half* As = (__half*)smem;
        int l = tid & 63, w = tid >> 6;
        int rowBase = (blockIdx.x - NBLKE) * GROWS;
        const float* __restrict__ xbase = x + (size_t)rowBase * F_INF;
        int colf = (l & 31) * 4;                 // float4 start col within chunk
        int rsub = l >> 5;                       // 0/1: row parity within pair

        f32x4 acc0 = {0.f, 0.f, 0.f, 0.f};
        f32x4 acc1 = {0.f, 0.f, 0.f, 0.f};
        f32x4 acc2 = {0.f, 0.f, 0.f, 0.f};

        const __half* __restrict__ Arow = &As[(w * 16 + (l & 15)) * ASTR + (l >> 4) * 8];

        float4 st[8];
        #pragma unroll
        for (int j = 0; j < 8; ++j) {
            int rj = w * 16 + j * 2 + rsub;
            st[j] = *(const float4*)(xbase + (size_t)rj * F_INF + colf);
        }
        for (int ch = 0; ch < F_INF / KCHG; ++ch) {  // 4 chunks, no barriers
            #pragma unroll
            for (int j = 0; j < 8; ++j) {
                int rj = w * 16 + j * 2 + rsub;
                union { __half2 h2[2]; float2 f2; } u;
                u.h2[0] = __floats2half2_rn(st[j].x, st[j].y);
                u.h2[1] = __floats2half2_rn(st[j].z, st[j].w);
                *(float2*)(&As[rj * ASTR + colf]) = u.f2;
            }
            if (ch + 1 < F_INF / KCHG) {         // issue next-chunk loads early
                #pragma unroll
                for (int j = 0; j < 8; ++j) {
                    int rj = w * 16 + j * 2 + rsub;
                    st[j] = *(const float4*)(xbase + (size_t)rj * F_INF
                                               + (ch + 1) * KCHG + colf);
                }
            }
            #pragma unroll
            for (int kkl = 0; kkl < 4; ++kkl) {  // 4 k-steps of K=32
                f16x8 a = *(const f16x8*)(Arow + kkl * 32);
                int kkg = ch * 4 + kkl;
                const __half* bp = Bf + ((size_t)kkg * 64 + l) * 8;
                f16x8 b0 = *(const f16x8*)(bp);
                f16x8 b1 = *(const f16x8*)(bp + 16 * 64 * 8);
                f16x8 b2 = *(const f16x8*)(bp + 2 * 16 * 64 * 8);
                acc0 = __builtin_amdgcn_mfma_f32_16x16x32_f16(a, b0, acc0, 0, 0, 0);
                acc1 = __builtin_amdgcn_mfma_f32_16x16x32_f16(a, b1, acc1, 0, 0, 0);
                acc2 = __builtin_amdgcn_mfma_f32_16x16x32_f16(a, b2, acc2, 0, 0, 0);
            }
        }
        int c = l & 15;
        int rbase = rowBase + w * 16 + (l >> 4) * 4;
        #pragma unroll
        for (int r = 0; r < 4; ++r) {
            int n = rbase + r;
            hbufH[(size_t)n * HID + c] = __floats2half2_rn(acc0[r], acc1[r]);
            rbufH[(size_t)n * HID + c] = __float2half(acc2[r]);
        }
    }
}

// ======================= P4: two-pass fine sort -> packed (w14|src18) CSR ============
__global__ __launch_bounds__(1024) void p4_buildcsr(
    const int* __restrict__ bucketStart, const int* __restrict__ bucketTotal,
    const unsigned long long* __restrict__ metaW,
    unsigned int* __restrict__ packedS, int* __restrict__ rowptr) {
    __shared__ int hist[NPB];
    __shared__ int wsum[16];
    int b = blockIdx.x, tid = threadIdx.x;
    int start = bucketStart[b], count = bucketTotal[b];
    int nn = min(NPB, N_NODES - b * NPB);
    hist[tid] = 0;
    __syncthreads();
    // pass 1: histogram (coalesced 8B re-read)
    for (int i = tid; i < count; i += 1024)
        atomicAdd(&hist[(int)(metaW[start + i] >> 32)], 1);
    __syncthreads();
    int v = hist[tid];
    int lane = tid & 63, wid = tid >> 6;
    int incl = v;
    #pragma unroll
    for (int o = 1; o < 64; o <<= 1) {
        int t = __shfl_up(incl, o, 64);
        if (lane >= o) incl += t;
    }
    if (lane == 63) wsum[wid] = incl;
    __syncthreads();
    int woff = 0;
    for (int w = 0; w < wid; ++w) woff += wsum[w];
    int excl = woff + incl - v;
    if (tid < nn) rowptr[b * NPB + tid] = start + excl;
    hist[tid] = excl;                            // becomes placement cursor
    __syncthreads();
    // pass 2: placement (low 32 bits already in final packed format)
    for (int i = tid; i < count; i += 1024) {
        unsigned long long m = metaW[start + i];
        int pos = start + atomicAdd(&hist[(int)(m >> 32)], 1);
        packedS[pos] = (unsigned int)m;
    }
}

// ==== agg1f: wave-per-node gather + ELU + fused W2/root2 transforms (4x unroll) ======
// h2buf/r2buf are DEDICATED buffers (must NOT alias hbufH).
__global__ __launch_bounds__(256) void agg1f_kernel(
    const unsigned int* __restrict__ packedS, const int* __restrict__ rowptr,
    const __half2* __restrict__ hbufH, const __half* __restrict__ rbufH,
    const float* __restrict__ bias1, const float* __restrict__ W2,
    const float* __restrict__ root2,
    __half2* __restrict__ h2buf, float* __restrict__ r2buf) {
    __shared__ float hsh[4][16];
    int wv = threadIdx.x >> 6;
    int n = blockIdx.x * 4 + wv;                   // grid exact: 50000*4 = 200000
    int lane = threadIdx.x & 63;
    int c = lane & 15, sub = lane >> 4;
    int beg = rowptr[n], end = rowptr[n + 1];
    float acc = 0.f;
    int p = beg + sub;
    for (; p + 12 < end; p += 16) {                // 4x unroll: 16 lines in flight/wave
        unsigned int m0 = packedS[p];
        unsigned int m1 = packedS[p + 4];
        unsigned int m2 = packedS[p + 8];
        unsigned int m3 = packedS[p + 12];
        float w0 = (float)(m0 >> 18) * (1.0f / 16383.0f);
        float w1 = (float)(m1 >> 18) * (1.0f / 16383.0f);
        float w2 = (float)(m2 >> 18) * (1.0f / 16383.0f);
        float w3 = (float)(m3 >> 18) * (1.0f / 16383.0f);
        float2 h0 = __half22float2(hbufH[(size_t)(m0 & 0x3FFFFu) * HID + c]);
        float2 h1 = __half22float2(hbufH[(size_t)(m1 & 0x3FFFFu) * HID + c]);
        float2 h2 = __half22float2(hbufH[(size_t)(m2 & 0x3FFFFu) * HID + c]);
        float2 h3 = __half22float2(hbufH[(size_t)(m3 & 0x3FFFFu) * HID + c]);
        acc += fmaf(w0, h0.y - h0.x, h0.x);
        acc += fmaf(w1, h1.y - h1.x, h1.x);
        acc += fmaf(w2, h2.y - h2.x, h2.x);
        acc += fmaf(w3, h3.y - h3.x, h3.x);
    }
    for (; p < end; p += 4) {
        unsigned int m = packedS[p];
        float w = (float)(m >> 18) * (1.0f / 16383.0f);
        float2 h = __half22float2(hbufH[(size_t)(m & 0x3FFFFu) * HID + c]);
        acc += fmaf(w, h.y - h.x, h.x);
    }
    acc += __shfl_xor(acc, 16, 64);
    acc += __shfl_xor(acc, 32, 64);
    if (sub == 0) {
        float invd = 1.0f / fmaxf((float)(end - beg), 1.0f);
        float r = __half2float(rbufH[(size_t)n * HID + c]);
        float vv = fmaf(acc, invd, r) + bias1[c];
        hsh[wv][c] = vv > 0.f ? vv : expm1f(vv);
    }
    // wave-internal LDS dependence (same wave writes then reads hsh[wv])
    if (lane < 8) {
        int j = lane;
        if (j < NCLS) {
            const float* __restrict__ W2b = W2 + HID * NCLS;
            float o0 = 0.f, o1 = 0.f, orr = 0.f;
            #pragma unroll
            for (int k = 0; k < HID; ++k) {
                float h = hsh[wv][k];
                o0  = fmaf(h, W2 [k * NCLS + j], o0);
                o1  = fmaf(h, W2b[k * NCLS + j], o1);
                orr = fmaf(h, root2[k * NCLS + j], orr);
            }
            h2buf[(size_t)n * 8 + j] = __floats2half2_rn(o0, o1);
            r2buf[(size_t)n * 8 + j] = orr;
        } else {
            h2buf[(size_t)n * 8 + 7] = __floats2half2_rn(0.f, 0.f);
            r2buf[(size_t)n * 8 + 7] = 0.f;
        }
    }
}

// ========== agg2: wave-per-node gather + log_softmax (8 slots, 4x unroll) ============
__global__ __launch_bounds__(256) void agg2_kernel(
    const unsigned int* __restrict__ packedS, const int* __restrict__ rowptr,
    const __half2* __restrict__ h2buf, const float* __restrict__ r2buf,
    const float* __restrict__ bias2, float* __restrict__ out) {
    int n = blockIdx.x * 4 + (threadIdx.x >> 6);
    int lane = threadIdx.x & 63;
    int j = lane & 7, sub = lane >> 3;
    int beg = rowptr[n], end = rowptr[n + 1];
    float acc = 0.f;
    int p = beg + sub;
    for (; p + 24 < end; p += 32) {                // 4x unroll: 32 lines in flight/wave
        unsigned int m0 = packedS[p];
        unsigned int m1 = packedS[p + 8];
        unsigned int m2 = packedS[p + 16];
        unsigned int m3 = packedS[p + 24];
        float w0 = (float)(m0 >> 18) * (1.0f / 16383.0f);
        float w1 = (float)(m1 >> 18) * (1.0f / 16383.0f);
        float w2 = (float)(m2 >> 18) * (1.0f / 16383.0f);
        float w3 = (float)(m3 >> 18) * (1.0f / 16383.0f);
        float2 h0 = __half22float2(h2buf[(size_t)(m0 & 0x3FFFFu) * 8 + j]);
        float2 h1 = __half22float2(h2buf[(size_t)(m1 & 0x3FFFFu) * 8 + j]);
        float2 h2 = __half22float2(h2buf[(size_t)(m2 & 0x3FFFFu) * 8 + j]);
        float2 h3 = __half22float2(h2buf[(size_t)(m3 & 0x3FFFFu) * 8 + j]);
        acc += fmaf(w0, h0.y - h0.x, h0.x);
        acc += fmaf(w1, h1.y - h1.x, h1.x);
        acc += fmaf(w2, h2.y - h2.x, h2.x);
        acc += fmaf(w3, h3.y - h3.x, h3.x);
    }
    for (; p < end; p += 8) {
        unsigned int m = packedS[p];
        float w = (float)(m >> 18) * (1.0f / 16383.0f);
        float2 h = __half22float2(h2buf[(size_t)(m & 0x3FFFFu) * 8 + j]);
        acc += fmaf(w, h.y - h.x, h.x);
    }
    acc += __shfl_xor(acc, 8, 64);
    acc += __shfl_xor(acc, 16, 64);
    acc += __shfl_xor(acc, 32, 64);
    if (sub == 0) {
        float invd = 1.0f / fmaxf((float)(end - beg), 1.0f);
        float v = fmaf(acc, invd, r2buf[(size_t)n * 8 + j]) + ((j < NCLS) ? bias2[j] : 0.f);
        if (j == NCLS) v = -INFINITY;
        float mx = v;
        mx = fmaxf(mx, __shfl_xor(mx, 1, 8));
        mx = fmaxf(mx, __shfl_xor(mx, 2, 8));
        mx = fmaxf(mx, __shfl_xor(mx, 4, 8));
        float ex = expf(v - mx);
        float sm = ex;
        sm += __shfl_xor(sm, 1, 8);
        sm += __shfl_xor(sm, 2, 8);
        sm += __shfl_xor(sm, 4, 8);
        float lse = mx + logf(sm);
        if (j < NCLS) out[(size_t)n * NCLS + j] = v - lse;
    }
}

extern "C" void kernel_launch(void* const* d_in, const int* in_sizes, int n_in,
                              void* d_out, int out_size, void* d_ws, size_t ws_size,
                              hipStream_t stream) {
    const float* x     = (const float*)d_in[0];
    const float* eattr = (const float*)d_in[1];
    const int*   src   = (const int*)d_in[2];
    const int*   dst   = (const int*)d_in[3];
    const float* W1    = (const float*)d_in[4];
    const float* root1 = (const float*)d_in[5];
    const float* bias1 = (const float*)d_in[6];
    const float* W2    = (const float*)d_in[7];
    const float* root2 = (const float*)d_in[8];
    const float* bias2 = (const float*)d_in[9];
    float* out = (float*)d_out;

    // ---------- workspace layout (~110 MB) ----------
    char* wp = (char*)d_ws;
    unsigned long long* metaW = (unsigned long long*)wp;  wp += (size_t)N_EDGES * 8; // 51.2 MB
    unsigned int* packedS = (unsigned int*)wp;  wp += (size_t)N_EDGES * 4;           // 25.6 MB
    int* blockOff    = (int*)wp;                wp += (size_t)NBUCKET * NBLKE * 4;   // 306 KB
    int* bucketTotal = (int*)wp;                wp += 1024 * 4;
    int* bucketStart = (int*)wp;                wp += 1024 * 4;
    int* rowptr      = (int*)wp;                wp += (size_t)(N_NODES + 4) * 4;     // 0.8 MB
    __half* Bf       = (__half*)wp;             wp += (size_t)3 * 16 * 64 * 8 * 2;   // 48 KB
    __half2* hbufH   = (__half2*)wp;            wp += (size_t)N_NODES * HID * 4;     // 12.8 MB
    __half*  rbufH   = (__half*)wp;             wp += (size_t)N_NODES * HID * 2;     // 6.4 MB
    __half2* h2buf   = (__half2*)wp;            wp += (size_t)N_NODES * 8 * 4;       // 6.4 MB (dedicated)
    float*   r2buf   = (float*)wp;              wp += (size_t)N_NODES * 8 * 4;       // 6.4 MB (dedicated)

    const int wave_blocks = N_NODES / 4;            // 50000 exact

    hipLaunchKernelGGL(packB_kernel, dim3((3 * 16 * 64 + 255) / 256), dim3(256), 0, stream,
                       W1, root1, Bf);
    hipLaunchKernelGGL(p1_bincount, dim3(NBLKE), dim3(256), 0, stream, dst, blockOff);
    hipLaunchKernelGGL(p2a_kernel, dim3(NBUCKET), dim3(256), 0, stream,
                       blockOff, bucketTotal);
    hipLaunchKernelGGL(p2b_kernel, dim3(1), dim3(256), 0, stream,
                       bucketTotal, bucketStart, rowptr);
    hipLaunchKernelGGL(gemm1p3_kernel, dim3(NBLKE + GEMM_BLOCKS), dim3(256), 0, stream,
                       x, Bf, hbufH, rbufH, dst, src, eattr,
                       blockOff, bucketStart, metaW);
    hipLaunchKernelGGL(p4_buildcsr, dim3(NBUCKET), dim3(1024), 0, stream,
                       bucketStart, bucketTotal, metaW, packedS, rowptr);
    hipLaunchKernelGGL(agg1f_kernel, dim3(wave_blocks), dim3(256), 0, stream,
                       packedS, rowptr, hbufH, rbufH, bias1, W2, root2, h2buf, r2buf);
    hipLaunchKernelGGL(agg2_kernel, dim3(wave_blocks), dim3(256), 0, stream,
                       packedS, rowptr, h2buf, r2buf, bias2, out);
}

// Round 27
// 492.848 us; speedup vs baseline: 1.0170x; 1.0170x over previous
//
#include <hip/hip_runtime.h>
#include <hip/hip_fp16.h>
#include <math.h>

#define N_NODES 200000
#define N_EDGES 6400000
#define F_INF   512
#define HID     16
#define NCLS    7

#define NPB      1024                              // nodes per bucket
#define NBUCKET  ((N_NODES + NPB - 1) / NPB)       // 196
#define CHUNK    16384
#define NBLKE    ((N_EDGES + CHUNK - 1) / CHUNK)   // 391

// ---- gemm1 (MFMA) geometry ----
#define GROWS 64     // rows per block (4 waves x 16)
#define KCHG  128    // K-chunk in fp32 elems (4 chunks of 128 = 512)
#define ASTR  136    // LDS row stride in halves (272B = 4 banks mod 32 -> <=2-way)
#define GEMM_BLOCKS (N_NODES / GROWS)              // 3125

typedef _Float16 f16x8 __attribute__((ext_vector_type(8)));
typedef float    f32x4 __attribute__((ext_vector_type(4)));

// ======================= pack (W1[0]|W1[1]|root1) into MFMA B-fragment order ========
__global__ __launch_bounds__(256) void packB_kernel(
    const float* __restrict__ W1, const float* __restrict__ root1,
    __half* __restrict__ Bf) {
    int tt = blockIdx.x * 256 + threadIdx.x;    // 3*16*64 = 3072
    if (tt >= 3 * 16 * 64) return;
    int lane = tt & 63, kk = (tt >> 6) & 15, t = tt >> 10;
    int col = lane & 15;
    int kbase = kk * 32 + (lane >> 4) * 8;
    const float* __restrict__ srcm = (t == 0) ? W1
                                   : (t == 1) ? (W1 + F_INF * HID) : root1;
    #pragma unroll
    for (int j = 0; j < 8; ++j)
        Bf[(size_t)tt * 8 + j] = __float2half(srcm[(kbase + j) * HID + col]);
}

// ======================= P1: per-block bucket histogram (int4 loads) =================
__global__ __launch_bounds__(256) void p1_bincount(const int* __restrict__ dst,
                                                   int* __restrict__ blockOff) {
    __shared__ int hist[4][NBUCKET];
    int tid = threadIdx.x, w = tid >> 6;
    for (int i = tid; i < 4 * NBUCKET; i += 256) hist[i / NBUCKET][i % NBUCKET] = 0;
    __syncthreads();
    size_t base = (size_t)blockIdx.x * CHUNK;
    #pragma unroll
    for (int i = 0; i < CHUNK / 1024; ++i) {       // 16 iters x 1024 edges
        size_t e = base + (size_t)i * 1024 + tid * 4;
        if (e < N_EDGES) {                          // tail block is 1024-granular
            int4 d4 = *(const int4*)(dst + e);
            atomicAdd(&hist[w][d4.x >> 10], 1);
            atomicAdd(&hist[w][d4.y >> 10], 1);
            atomicAdd(&hist[w][d4.z >> 10], 1);
            atomicAdd(&hist[w][d4.w >> 10], 1);
        }
    }
    __syncthreads();
    for (int i = tid; i < NBUCKET; i += 256)
        blockOff[(size_t)i * NBLKE + blockIdx.x] =
            hist[0][i] + hist[1][i] + hist[2][i] + hist[3][i];
}

// ======================= P2a: per-bucket scan over blocks =======================
__global__ __launch_bounds__(256) void p2a_kernel(int* __restrict__ blockOff,
                                                  int* __restrict__ bucketTotal) {
    __shared__ int wsum[4];
    int b = blockIdx.x, tid = threadIdx.x;
    size_t rowb = (size_t)b * NBLKE;
    int i0 = tid * 2, i1 = i0 + 1;
    int v0 = (i0 < NBLKE) ? blockOff[rowb + i0] : 0;
    int v1 = (i1 < NBLKE) ? blockOff[rowb + i1] : 0;
    int s = v0 + v1;
    int lane = tid & 63, wid = tid >> 6;
    int incl = s;
    #pragma unroll
    for (int o = 1; o < 64; o <<= 1) {
        int t = __shfl_up(incl, o, 64);
        if (lane >= o) incl += t;
    }
    if (lane == 63) wsum[wid] = incl;
    __syncthreads();
    int woff = 0;
    for (int w = 0; w < wid; ++w) woff += wsum[w];
    int excl = woff + incl - s;
    if (i0 < NBLKE) blockOff[rowb + i0] = excl;
    if (i1 < NBLKE) blockOff[rowb + i1] = excl + v0;
    if (tid == 255) bucketTotal[b] = woff + incl;
}

// ======================= P2b: scan bucket totals -> bucketStart =======================
__global__ __launch_bounds__(256) void p2b_kernel(const int* __restrict__ bucketTotal,
                                                  int* __restrict__ bucketStart,
                                                  int* __restrict__ rowptr) {
    __shared__ int wsum[4];
    int tid = threadIdx.x;
    int base = tid * 4;
    int v[4]; int s = 0;
    #pragma unroll
    for (int q = 0; q < 4; ++q) {
        int idx = base + q;
        v[q] = (idx < NBUCKET) ? bucketTotal[idx] : 0;
        s += v[q];
    }
    int lane = tid & 63, wid = tid >> 6;
    int incl = s;
    #pragma unroll
    for (int o = 1; o < 64; o <<= 1) {
        int t = __shfl_up(incl, o, 64);
        if (lane >= o) incl += t;
    }
    if (lane == 63) wsum[wid] = incl;
    __syncthreads();
    int woff = 0;
    for (int w = 0; w < wid; ++w) woff += wsum[w];
    int run = woff + incl - s;
    #pragma unroll
    for (int q = 0; q < 4; ++q) {
        int idx = base + q;
        if (idx < NBUCKET) bucketStart[idx] = run;
        run += v[q];
    }
    if (tid == 0) rowptr[N_NODES] = N_EDGES;
}

// ============ fused: P3 binned scatter (blocks 0..390) + layer-1 GEMM (rest) =========
// p3 writes ONE 8-byte payload per edge: (local[10b]<<32) | (wq14<<18) | src18.
__global__ __launch_bounds__(256) void gemm1p3_kernel(
    const float* __restrict__ x, const __half* __restrict__ Bf,
    __half2* __restrict__ hbufH, __half* __restrict__ rbufH,
    const int* __restrict__ dst, const int* __restrict__ src,
    const float* __restrict__ eattr,
    const int* __restrict__ blockOff, const int* __restrict__ bucketStart,
    unsigned long long* __restrict__ metaW) {
    __shared__ char smem[GROWS * ASTR * 2];      // 17408 B, aliased by both paths
    int tid = threadIdx.x;

    if (blockIdx.x < NBLKE) {
        // ---- P3: binned scatter of payload ----
        int bb = blockIdx.x;
        int* cur = (int*)smem;                   // 196 ints
        for (int i = tid; i < NBUCKET; i += 256)
            cur[i] = bucketStart[i] + blockOff[(size_t)i * NBLKE + bb];
        __syncthreads();
        size_t base = (size_t)bb * CHUNK;
        for (int i = 0; i < CHUNK / 256; ++i) {
            size_t e = base + (size_t)i * 256 + tid;
            if (e < N_EDGES) {
                int d = dst[e];
                int b = d >> 10;
                int slot = atomicAdd(&cur[b], 1);
                float w = fminf(fmaxf(eattr[e], 0.f), 1.f);
                unsigned int wq = (unsigned int)(w * 16383.0f + 0.5f);
                unsigned int lo = (wq << 18) | (unsigned int)src[e];
                metaW[slot] = ((unsigned long long)(d & 1023) << 32) | lo;
            }
        }
    } else {
        // ---- layer-1 GEMM via MFMA (KCHG=128, reg-prefetch of next chunk) ----
        __half* As = (__half*)smem;
        int l = tid & 63, w = tid >> 6;
        int rowBase = (blockIdx.x - NBLKE) * GROWS;
        const float* __restrict__ xbase = x + (size_t)rowBase * F_INF;
        int colf = (l & 31) * 4;                 // float4 start col within chunk
        int rsub = l >> 5;                       // 0/1: row parity within pair

        f32x4 acc0 = {0.f, 0.f, 0.f, 0.f};
        f32x4 acc1 = {0.f, 0.f, 0.f, 0.f};
        f32x4 acc2 = {0.f, 0.f, 0.f, 0.f};

        const __half* __restrict__ Arow = &As[(w * 16 + (l & 15)) * ASTR + (l >> 4) * 8];

        float4 st[8];
        #pragma unroll
        for (int j = 0; j < 8; ++j) {
            int rj = w * 16 + j * 2 + rsub;
            st[j] = *(const float4*)(xbase + (size_t)rj * F_INF + colf);
        }
        for (int ch = 0; ch < F_INF / KCHG; ++ch) {  // 4 chunks
            __syncthreads();                     // LDS free (prev compute done)
            #pragma unroll
            for (int j = 0; j < 8; ++j) {
                int rj = w * 16 + j * 2 + rsub;
                union { __half2 h2[2]; float2 f2; } u;
                u.h2[0] = __floats2half2_rn(st[j].x, st[j].y);
                u.h2[1] = __floats2half2_rn(st[j].z, st[j].w);
                *(float2*)(&As[rj * ASTR + colf]) = u.f2;
            }
            if (ch + 1 < F_INF / KCHG) {         // issue next-chunk loads early
                #pragma unroll
                for (int j = 0; j < 8; ++j) {
                    int rj = w * 16 + j * 2 + rsub;
                    st[j] = *(const float4*)(xbase + (size_t)rj * F_INF
                                               + (ch + 1) * KCHG + colf);
                }
            }
            __syncthreads();                     // LDS ready
            #pragma unroll
            for (int kkl = 0; kkl < 4; ++kkl) {  // 4 k-steps of K=32
                f16x8 a = *(const f16x8*)(Arow + kkl * 32);
                int kkg = ch * 4 + kkl;
                const __half* bp = Bf + ((size_t)kkg * 64 + l) * 8;
                f16x8 b0 = *(const f16x8*)(bp);
                f16x8 b1 = *(const f16x8*)(bp + 16 * 64 * 8);
                f16x8 b2 = *(const f16x8*)(bp + 2 * 16 * 64 * 8);
                acc0 = __builtin_amdgcn_mfma_f32_16x16x32_f16(a, b0, acc0, 0, 0, 0);
                acc1 = __builtin_amdgcn_mfma_f32_16x16x32_f16(a, b1, acc1, 0, 0, 0);
                acc2 = __builtin_amdgcn_mfma_f32_16x16x32_f16(a, b2, acc2, 0, 0, 0);
            }
        }
        int c = l & 15;
        int rbase = rowBase + w * 16 + (l >> 4) * 4;
        #pragma unroll
        for (int r = 0; r < 4; ++r) {
            int n = rbase + r;
            hbufH[(size_t)n * HID + c] = __floats2half2_rn(acc0[r], acc1[r]);
            rbufH[(size_t)n * HID + c] = __float2half(acc2[r]);
        }
    }
}

// ======================= P4: two-pass fine sort -> packed (w14|src18) CSR ============
__global__ __launch_bounds__(1024) void p4_buildcsr(
    const int* __restrict__ bucketStart, const int* __restrict__ bucketTotal,
    const unsigned long long* __restrict__ metaW,
    unsigned int* __restrict__ packedS, int* __restrict__ rowptr) {
    __shared__ int hist[NPB];
    __shared__ int wsum[16];
    int b = blockIdx.x, tid = threadIdx.x;
    int start = bucketStart[b], count = bucketTotal[b];
    int nn = min(NPB, N_NODES - b * NPB);
    hist[tid] = 0;
    __syncthreads();
    // pass 1: histogram (coalesced 8B re-read)
    for (int i = tid; i < count; i += 1024)
        atomicAdd(&hist[(int)(metaW[start + i] >> 32)], 1);
    __syncthreads();
    int v = hist[tid];
    int lane = tid & 63, wid = tid >> 6;
    int incl = v;
    #pragma unroll
    for (int o = 1; o < 64; o <<= 1) {
        int t = __shfl_up(incl, o, 64);
        if (lane >= o) incl += t;
    }
    if (lane == 63) wsum[wid] = incl;
    __syncthreads();
    int woff = 0;
    for (int w = 0; w < wid; ++w) woff += wsum[w];
    int excl = woff + incl - v;
    if (tid < nn) rowptr[b * NPB + tid] = start + excl;
    hist[tid] = excl;                            // becomes placement cursor
    __syncthreads();
    // pass 2: placement (low 32 bits already in final packed format)
    for (int i = tid; i < count; i += 1024) {
        unsigned long long m = metaW[start + i];
        int pos = start + atomicAdd(&hist[(int)(m >> 32)], 1);
        packedS[pos] = (unsigned int)m;
    }
}

// ==== agg1f: wave-per-node gather + ELU + fused W2/root2 transforms (4x unroll) ======
// h2buf/r2buf are DEDICATED buffers (must NOT alias hbufH).
__global__ __launch_bounds__(256) void agg1f_kernel(
    const unsigned int* __restrict__ packedS, const int* __restrict__ rowptr,
    const __half2* __restrict__ hbufH, const __half* __restrict__ rbufH,
    const float* __restrict__ bias1, const float* __restrict__ W2,
    const float* __restrict__ root2,
    __half2* __restrict__ h2buf, float* __restrict__ r2buf) {
    __shared__ float hsh[4][16];
    int wv = threadIdx.x >> 6;
    int n = blockIdx.x * 4 + wv;                   // grid exact: 50000*4 = 200000
    int lane = threadIdx.x & 63;
    int c = lane & 15, sub = lane >> 4;
    int beg = rowptr[n], end = rowptr[n + 1];
    float acc = 0.f;
    int p = beg + sub;
    for (; p + 12 < end; p += 16) {                // 4x unroll: 16 lines in flight/wave
        unsigned int m0 = packedS[p];
        unsigned int m1 = packedS[p + 4];
        unsigned int m2 = packedS[p + 8];
        unsigned int m3 = packedS[p + 12];
        float w0 = (float)(m0 >> 18) * (1.0f / 16383.0f);
        float w1 = (float)(m1 >> 18) * (1.0f / 16383.0f);
        float w2 = (float)(m2 >> 18) * (1.0f / 16383.0f);
        float w3 = (float)(m3 >> 18) * (1.0f / 16383.0f);
        float2 h0 = __half22float2(hbufH[(size_t)(m0 & 0x3FFFFu) * HID + c]);
        float2 h1 = __half22float2(hbufH[(size_t)(m1 & 0x3FFFFu) * HID + c]);
        float2 h2 = __half22float2(hbufH[(size_t)(m2 & 0x3FFFFu) * HID + c]);
        float2 h3 = __half22float2(hbufH[(size_t)(m3 & 0x3FFFFu) * HID + c]);
        acc += fmaf(w0, h0.y - h0.x, h0.x);
        acc += fmaf(w1, h1.y - h1.x, h1.x);
        acc += fmaf(w2, h2.y - h2.x, h2.x);
        acc += fmaf(w3, h3.y - h3.x, h3.x);
    }
    for (; p < end; p += 4) {
        unsigned int m = packedS[p];
        float w = (float)(m >> 18) * (1.0f / 16383.0f);
        float2 h = __half22float2(hbufH[(size_t)(m & 0x3FFFFu) * HID + c]);
        acc += fmaf(w, h.y - h.x, h.x);
    }
    acc += __shfl_xor(acc, 16, 64);
    acc += __shfl_xor(acc, 32, 64);
    if (sub == 0) {
        float invd = 1.0f / fmaxf((float)(end - beg), 1.0f);
        float r = __half2float(rbufH[(size_t)n * HID + c]);
        float vv = fmaf(acc, invd, r) + bias1[c];
        hsh[wv][c] = vv > 0.f ? vv : expm1f(vv);
    }
    // wave-internal LDS dependence (same wave writes then reads hsh[wv])
    if (lane < 8) {
        int j = lane;
        if (j < NCLS) {
            const float* __restrict__ W2b = W2 + HID * NCLS;
            float o0 = 0.f, o1 = 0.f, orr = 0.f;
            #pragma unroll
            for (int k = 0; k < HID; ++k) {
                float h = hsh[wv][k];
                o0  = fmaf(h, W2 [k * NCLS + j], o0);
                o1  = fmaf(h, W2b[k * NCLS + j], o1);
                orr = fmaf(h, root2[k * NCLS + j], orr);
            }
            h2buf[(size_t)n * 8 + j] = __floats2half2_rn(o0, o1);
            r2buf[(size_t)n * 8 + j] = orr;
        } else {
            h2buf[(size_t)n * 8 + 7] = __floats2half2_rn(0.f, 0.f);
            r2buf[(size_t)n * 8 + 7] = 0.f;
        }
    }
}

// ========== agg2: wave-per-node gather + log_softmax (8 slots, 4x unroll) ============
__global__ __launch_bounds__(256) void agg2_kernel(
    const unsigned int* __restrict__ packedS, const int* __restrict__ rowptr,
    const __half2* __restrict__ h2buf, const float* __restrict__ r2buf,
    const float* __restrict__ bias2, float* __restrict__ out) {
    int n = blockIdx.x * 4 + (threadIdx.x >> 6);
    int lane = threadIdx.x & 63;
    int j = lane & 7, sub = lane >> 3;
    int beg = rowptr[n], end = rowptr[n + 1];
    float acc = 0.f;
    int p = beg + sub;
    for (; p + 24 < end; p += 32) {                // 4x unroll: 32 lines in flight/wave
        unsigned int m0 = packedS[p];
        unsigned int m1 = packedS[p + 8];
        unsigned int m2 = packedS[p + 16];
        unsigned int m3 = packedS[p + 24];
        float w0 = (float)(m0 >> 18) * (1.0f / 16383.0f);
        float w1 = (float)(m1 >> 18) * (1.0f / 16383.0f);
        float w2 = (float)(m2 >> 18) * (1.0f / 16383.0f);
        float w3 = (float)(m3 >> 18) * (1.0f / 16383.0f);
        float2 h0 = __half22float2(h2buf[(size_t)(m0 & 0x3FFFFu) * 8 + j]);
        float2 h1 = __half22float2(h2buf[(size_t)(m1 & 0x3FFFFu) * 8 + j]);
        float2 h2 = __half22float2(h2buf[(size_t)(m2 & 0x3FFFFu) * 8 + j]);
        float2 h3 = __half22float2(h2buf[(size_t)(m3 & 0x3FFFFu) * 8 + j]);
        acc += fmaf(w0, h0.y - h0.x, h0.x);
        acc += fmaf(w1, h1.y - h1.x, h1.x);
        acc += fmaf(w2, h2.y - h2.x, h2.x);
        acc += fmaf(w3, h3.y - h3.x, h3.x);
    }
    for (; p < end; p += 8) {
        unsigned int m = packedS[p];
        float w = (float)(m >> 18) * (1.0f / 16383.0f);
        float2 h = __half22float2(h2buf[(size_t)(m & 0x3FFFFu) * 8 + j]);
        acc += fmaf(w, h.y - h.x, h.x);
    }
    acc += __shfl_xor(acc, 8, 64);
    acc += __shfl_xor(acc, 16, 64);
    acc += __shfl_xor(acc, 32, 64);
    if (sub == 0) {
        float invd = 1.0f / fmaxf((float)(end - beg), 1.0f);
        float v = fmaf(acc, invd, r2buf[(size_t)n * 8 + j]) + ((j < NCLS) ? bias2[j] : 0.f);
        if (j == NCLS) v = -INFINITY;
        float mx = v;
        mx = fmaxf(mx, __shfl_xor(mx, 1, 8));
        mx = fmaxf(mx, __shfl_xor(mx, 2, 8));
        mx = fmaxf(mx, __shfl_xor(mx, 4, 8));
        float ex = expf(v - mx);
        float sm = ex;
        sm += __shfl_xor(sm, 1, 8);
        sm += __shfl_xor(sm, 2, 8);
        sm += __shfl_xor(sm, 4, 8);
        float lse = mx + logf(sm);
        if (j < NCLS) out[(size_t)n * NCLS + j] = v - lse;
    }
}

extern "C" void kernel_launch(void* const* d_in, const int* in_sizes, int n_in,
                              void* d_out, int out_size, void* d_ws, size_t ws_size,
                              hipStream_t stream) {
    const float* x     = (const float*)d_in[0];
    const float* eattr = (const float*)d_in[1];
    const int*   src   = (const int*)d_in[2];
    const int*   dst   = (const int*)d_in[3];
    const float* W1    = (const float*)d_in[4];
    const float* root1 = (const float*)d_in[5];
    const float* bias1 = (const float*)d_in[6];
    const float* W2    = (const float*)d_in[7];
    const float* root2 = (const float*)d_in[8];
    const float* bias2 = (const float*)d_in[9];
    float* out = (float*)d_out;

    // ---------- workspace layout (~110 MB) ----------
    char* wp = (char*)d_ws;
    unsigned long long* metaW = (unsigned long long*)wp;  wp += (size_t)N_EDGES * 8; // 51.2 MB
    unsigned int* packedS = (unsigned int*)wp;  wp += (size_t)N_EDGES * 4;           // 25.6 MB
    int* blockOff    = (int*)wp;                wp += (size_t)NBUCKET * NBLKE * 4;   // 306 KB
    int* bucketTotal = (int*)wp;                wp += 1024 * 4;
    int* bucketStart = (int*)wp;                wp += 1024 * 4;
    int* rowptr      = (int*)wp;                wp += (size_t)(N_NODES + 4) * 4;     // 0.8 MB
    __half* Bf       = (__half*)wp;             wp += (size_t)3 * 16 * 64 * 8 * 2;   // 48 KB
    __half2* hbufH   = (__half2*)wp;            wp += (size_t)N_NODES * HID * 4;     // 12.8 MB
    __half*  rbufH   = (__half*)wp;             wp += (size_t)N_NODES * HID * 2;     // 6.4 MB
    __half2* h2buf   = (__half2*)wp;            wp += (size_t)N_NODES * 8 * 4;       // 6.4 MB (dedicated)
    float*   r2buf   = (float*)wp;              wp += (size_t)N_NODES * 8 * 4;       // 6.4 MB (dedicated)

    const int wave_blocks = N_NODES / 4;            // 50000 exact

    hipLaunchKernelGGL(packB_kernel, dim3((3 * 16 * 64 + 255) / 256), dim3(256), 0, stream,
                       W1, root1, Bf);
    hipLaunchKernelGGL(p1_bincount, dim3(NBLKE), dim3(256), 0, stream, dst, blockOff);
    hipLaunchKernelGGL(p2a_kernel, dim3(NBUCKET), dim3(256), 0, stream,
                       blockOff, bucketTotal);
    hipLaunchKernelGGL(p2b_kernel, dim3(1), dim3(256), 0, stream,
                       bucketTotal, bucketStart, rowptr);
    hipLaunchKernelGGL(gemm1p3_kernel, dim3(NBLKE + GEMM_BLOCKS), dim3(256), 0, stream,
                       x, Bf, hbufH, rbufH, dst, src, eattr,
                       blockOff, bucketStart, metaW);
    hipLaunchKernelGGL(p4_buildcsr, dim3(NBUCKET), dim3(1024), 0, stream,
                       bucketStart, bucketTotal, metaW, packedS, rowptr);
    hipLaunchKernelGGL(agg1f_kernel, dim3(wave_blocks), dim3(256), 0, stream,
                       packedS, rowptr, hbufH, rbufH, bias1, W2, root2, h2buf, r2buf);
    hipLaunchKernelGGL(agg2_kernel, dim3(wave_blocks), dim3(256), 0, stream,
                       packedS, rowptr, h2buf, r2buf, bias2, out);
}